// Round 5
// baseline (513.422 us; speedup 1.0000x reference)
//
#include <hip/hip_runtime.h>

#define KMAX 17            // edges per thread in count/scatter
#define CTH  256           // threads per count/scatter block
#define EVB  (KMAX * CTH)  // 4352 events per block

typedef __attribute__((ext_vector_type(8))) short short8;
typedef __attribute__((ext_vector_type(4))) float f32x4;

__device__ __forceinline__ unsigned short f2bf(float x) {   // RNE
    unsigned u = __float_as_uint(x);
    u += 0x7FFF + ((u >> 16) & 1);
    return (unsigned short)(u >> 16);
}

__device__ __forceinline__ void gld_lds16(const float* g, float* l) {
    __builtin_amdgcn_global_load_lds(
        (const __attribute__((address_space(1))) unsigned*)g,
        (__attribute__((address_space(3))) unsigned*)l, 16, 0, 0);
}

// ---------------- count: per-(bucket,block) dst table + degree atomics ----------
// v6: out-deg/in-deg via direct global atomics (6.4M u32 atomics, L2-resident
// 800KB targets) -> srecs, sstage, the srecs dump, and ALL of k_degA deleted;
// scatter + tab + scans are dst-only (half the work).
__global__ __launch_bounds__(CTH) void k_count(const int* __restrict__ src,
        const int* __restrict__ dst, int* __restrict__ tab,
        unsigned* __restrict__ odeg, unsigned* __restrict__ ideg,
        int E, int NBK, int NBC) {
    __shared__ int cD[512];
    const int t = threadIdx.x;
    for (int i = t; i < 512; i += CTH) cD[i] = 0;
    __syncthreads();
    const int e0 = blockIdx.x * EVB;
    int e1 = e0 + EVB; if (e1 > E) e1 = E;
    for (int e = e0 + t; e < e1; e += CTH) {
        const int s = src[e], d = dst[e];
        atomicAdd(&odeg[s], 1u);
        atomicAdd(&ideg[d], 1u);
        atomicAdd(&cD[d >> 8], 1);
    }
    __syncthreads();
    const int col = (blockIdx.x & 7) * (NBC >> 3) + (blockIdx.x >> 3);
    for (int b = t; b < NBK; b += CTH)
        tab[(size_t)b * NBC + col] = cD[b];
}

// ---------------- hierarchical exclusive scan (3 phases) ----------------
__global__ __launch_bounds__(256) void k_scanA(const int* __restrict__ tab,
                                               int* __restrict__ bsum, int Ntab) {
    __shared__ int red[256];
    const int t = threadIdx.x;
    const int base = blockIdx.x * 2048 + t * 8;
    int s = 0;
#pragma unroll
    for (int k = 0; k < 8; ++k) { int i = base + k; if (i < Ntab) s += tab[i]; }
    red[t] = s; __syncthreads();
    for (int off = 128; off > 0; off >>= 1) {
        if (t < off) red[t] += red[t + off];
        __syncthreads();
    }
    if (t == 0) bsum[blockIdx.x] = red[0];
}

__global__ __launch_bounds__(256) void k_scanB(int* __restrict__ bsum, int NB) {
    __shared__ int sc[256];
    __shared__ int carry;
    const int t = threadIdx.x;
    if (t == 0) carry = 0;
    __syncthreads();
    for (int base = 0; base < NB; base += 256) {
        const int i = base + t;
        const int v = (i < NB) ? bsum[i] : 0;
        sc[t] = v; __syncthreads();
        for (int off = 1; off < 256; off <<= 1) {
            int add = (t >= off) ? sc[t - off] : 0;
            __syncthreads();
            sc[t] += add;
            __syncthreads();
        }
        if (i < NB) bsum[i] = carry + sc[t] - v;   // exclusive
        __syncthreads();
        if (t == 255) carry += sc[255];
        __syncthreads();
    }
}

__global__ __launch_bounds__(256) void k_scanC(int* __restrict__ tab,
                                               const int* __restrict__ bsum, int Ntab) {
    __shared__ int sc[256];
    const int t = threadIdx.x;
    const int base = blockIdx.x * 2048 + t * 8;
    int v[8]; int s = 0;
#pragma unroll
    for (int k = 0; k < 8; ++k) { int i = base + k; v[k] = (i < Ntab) ? tab[i] : 0; s += v[k]; }
    sc[t] = s; __syncthreads();
    for (int off = 1; off < 256; off <<= 1) {
        int add = (t >= off) ? sc[t - off] : 0;
        __syncthreads();
        sc[t] += add;
        __syncthreads();
    }
    int run = bsum[blockIdx.x] + sc[t] - s;
#pragma unroll
    for (int k = 0; k < 8; ++k) {
        int i = base + k;
        if (i < Ntab) { tab[i] = run; run += v[k]; }
    }
    if (base < Ntab && Ntab <= base + 8) tab[Ntab] = run;   // sentinel = E
}

// ---------------- scatter (dst only): LDS-staged, bucket-ordered dump ----------
__global__ __launch_bounds__(CTH) void k_scatter(const int* __restrict__ src,
        const int* __restrict__ dst, const int* __restrict__ tab,
        unsigned* __restrict__ drecs, int E, int NBK, int NBC) {
    __shared__ unsigned dstage[EVB];          // 17.4 KB
    __shared__ int off[513];                  // exclusive offsets + total
    __shared__ int pos[512];                  // running counters
    __shared__ int bD[512];
    __shared__ int red[256];
    const int t = threadIdx.x;
    pos[t] = 0; pos[t + 256] = 0;
    __syncthreads();
    const int e0 = blockIdx.x * EVB;
    const int e1full = e0 + EVB;
    const int e1 = (e1full > E) ? E : e1full;

    int sv[KMAX], dv[KMAX];
#pragma unroll
    for (int k = 0; k < KMAX; ++k) {
        const int e = e0 + k * CTH + t;
        if (e < e1) {
            sv[k] = src[e]; dv[k] = dst[e];
            atomicAdd(&pos[dv[k] >> 8], 1);
        }
    }
    __syncthreads();
    const int v0 = pos[2 * t], v1 = pos[2 * t + 1];
    const int ps = v0 + v1;
    red[t] = ps;
    __syncthreads();
    for (int o = 1; o < 256; o <<= 1) {
        int add = (t >= o) ? red[t - o] : 0;
        __syncthreads();
        red[t] += add;
        __syncthreads();
    }
    const int base = red[t] - ps;
    off[2 * t] = base;
    off[2 * t + 1] = base + v0;
    if (t == 255) off[512] = red[255];
    __syncthreads();
    pos[t] = off[t]; pos[t + 256] = off[t + 256];
    __syncthreads();
#pragma unroll
    for (int k = 0; k < KMAX; ++k) {
        const int e = e0 + k * CTH + t;
        if (e < e1) {
            const int d = dv[k];
            const int rd = atomicAdd(&pos[d >> 8], 1);
            dstage[rd] = ((unsigned)sv[k] << 8) | (unsigned)(d & 255);
        }
    }
    const int col = (blockIdx.x & 7) * (NBC >> 3) + (blockIdx.x >> 3);
    for (int b = t; b < NBK; b += CTH)
        bD[b] = tab[(size_t)b * NBC + col];
    __syncthreads();
    const int tot = e1 - e0;
    for (int slot = t; slot < tot; slot += CTH) {
        int lo = 0, hi = NBK;
        while (hi - lo > 1) {
            const int md = (lo + hi) >> 1;
            if (off[md] <= slot) lo = md; else hi = md;
        }
        drecs[bD[lo] + slot - off[lo]] = dstage[slot];
    }
}

// ---------------- degrees -> per-node norms ----------------
__global__ __launch_bounds__(256) void k_norm(const unsigned* __restrict__ odeg,
        const unsigned* __restrict__ ideg,
        float* __restrict__ ns, float* __restrict__ nd, int N) {
    const int node = blockIdx.x * 256 + threadIdx.x;
    if (node >= N) return;
    ns[node] = rsqrtf(fmaxf((float)odeg[node], 1.f));
    nd[node] = rsqrtf(fmaxf((float)ideg[node], 1.f));
}

// ---------------- projection via MFMA (2-term bf16 split) ----------------
// X@W on the matrix pipe. W = Wh+Wl, X = Xh+Xl (bf16 truncate + bf16(RNE)
// remainder); XhWh + XhWl + XlWh gives fp32-grade accuracy. W fragments in
// 64 VGPR/lane loaded once; X staged wave-privately via global_load_lds
// (one instr = one contiguous 1KB row), no barriers, next tile prefetched
// under the epilogue. C/D layout: col=lane&15, row=(lane>>4)*4+reg.
// LDS swizzle: row-XOR (r&7)<<4 on the gld_lds GLOBAL source and the same
// involution on the ds_read offset (both-sides rule).
__global__ __launch_bounds__(256) void k_gemm(const float* __restrict__ X,
        const float* __restrict__ W, const float* __restrict__ ns,
        unsigned short* __restrict__ Hb, int N, int NT) {
    __shared__ float lx[4][16][256];           // 64 KB, 16 KB per wave
    const int t = threadIdx.x;
    const int wv = t >> 6, l = t & 63;
    const int c = l & 15, g = l >> 4;
    float* myx = &lx[wv][0][0];

    // ---- W fragments, once per wave: slot (kc,g,j) = W[kc*32+g*8+j][c] ----
    short8 wh[8], wl[8];
#pragma unroll
    for (int kc = 0; kc < 8; ++kc) {
#pragma unroll
        for (int j = 0; j < 8; ++j) {
            const float w = W[(kc * 32 + g * 8 + j) * 16 + c];
            const unsigned u = __float_as_uint(w);
            const unsigned short h = (unsigned short)(u >> 16);     // truncate
            const float hf = __uint_as_float((unsigned)h << 16);
            wh[kc][j] = (short)h;
            wl[kc][j] = (short)f2bf(w - hf);
        }
    }

    const int wgid = blockIdx.x * 4 + wv;
    const int wstr = gridDim.x * 4;

    int tile = wgid;
    if (tile < NT) {                           // prologue stage
        const int r0 = tile * 16;
#pragma unroll
        for (int r = 0; r < 16; ++r) {
            const int row = r0 + r;
            if (row < N)
                gld_lds16((const float*)((const char*)&X[(size_t)row * 256]
                           + ((l * 16) ^ ((r & 7) << 4))), &myx[r * 256]);
        }
    }

    for (; tile < NT; tile += wstr) {
        asm volatile("s_waitcnt vmcnt(0)" ::: "memory");
        __builtin_amdgcn_sched_barrier(0);

        const int sig = (c & 7) << 4;          // this lane's A-row swizzle
        const char* base = (const char*)&myx[c * 256];
        f32x4 acc = {0.f, 0.f, 0.f, 0.f};
#pragma unroll
        for (int kc = 0; kc < 8; ++kc) {
            const float4 xa = *(const float4*)(base + kc * 128 + ((g * 32) ^ sig));
            const float4 xb = *(const float4*)(base + kc * 128 + ((g * 32 + 16) ^ sig));
            const float xs[8] = {xa.x, xa.y, xa.z, xa.w, xb.x, xb.y, xb.z, xb.w};
            short8 ah, al;
#pragma unroll
            for (int j = 0; j < 8; ++j) {
                const unsigned u = __float_as_uint(xs[j]);
                const unsigned short h = (unsigned short)(u >> 16);
                const float hf = __uint_as_float((unsigned)h << 16);
                ah[j] = (short)h;
                al[j] = (short)f2bf(xs[j] - hf);
            }
            acc = __builtin_amdgcn_mfma_f32_16x16x32_bf16(ah, wh[kc], acc, 0, 0, 0);
            acc = __builtin_amdgcn_mfma_f32_16x16x32_bf16(ah, wl[kc], acc, 0, 0, 0);
            acc = __builtin_amdgcn_mfma_f32_16x16x32_bf16(al, wh[kc], acc, 0, 0, 0);
        }

        const int nt2 = tile + wstr;           // prefetch next tile under epilogue
        if (nt2 < NT) {
            const int r0 = nt2 * 16;
#pragma unroll
            for (int r = 0; r < 16; ++r) {
                const int row = r0 + r;
                if (row < N)
                    gld_lds16((const float*)((const char*)&X[(size_t)row * 256]
                               + ((l * 16) ^ ((r & 7) << 4))), &myx[r * 256]);
            }
        }

        // epilogue: C/D row = g*4 + v, col = c
        const int rowb = tile * 16 + g * 4;
#pragma unroll
        for (int v = 0; v < 4; ++v) {
            const int row = rowb + v;
            if (row < N)
                Hb[(size_t)row * 16 + c] = f2bf(acc[v] * ns[row]);
        }
    }
}

// ---------------- per-bucket edge accumulation in REGISTERS ----------------
__global__ __launch_bounds__(256) void k_gaccum(const unsigned* __restrict__ drecs,
        const int* __restrict__ tab, const int* __restrict__ seg,
        const float* __restrict__ nd, const unsigned short* __restrict__ Hb,
        float* __restrict__ outagg, int N, int NBK, int NBC, int E, int G) {
    __shared__ float lnd[256];
    __shared__ int   lgi[256];
    __shared__ float lhist[256];
    __shared__ float wred[4 * 48];
    const int b = blockIdx.x >> 1, half = blockIdx.x & 1;
    const int t = threadIdx.x;
    const int node0 = b << 8;
    const int gf = seg[node0];
    lhist[t] = 0.f;
    const int node = node0 + t;
    if (node < N) {
        lnd[t] = nd[node];
        lgi[t] = seg[node] - gf;
    }
    __syncthreads();
    const int dA0 = tab[(size_t)b * NBC];
    const int dA1 = tab[(size_t)(b + 1) * NBC];
    const int mid = dA0 + ((dA1 - dA0) >> 1);
    const int i0 = half ? mid : dA0;
    const int i1 = half ? dA1 : mid;

    float a0[16], a1[16], a2[16];
#pragma unroll
    for (int j = 0; j < 16; ++j) { a0[j] = 0.f; a1[j] = 0.f; a2[j] = 0.f; }

    for (int i = i0 + t; i < i1; i += 256) {
        const unsigned r = drecs[i];
        const int dlow = r & 255;
        const int s = (int)(r >> 8);
        const float w = lnd[dlow];
        const int gi = lgi[dlow];
        const uint4* hp = (const uint4*)(Hb + (size_t)s * 16);
        const uint4 h0 = hp[0];
        const uint4 h1 = hp[1];
        if (gi < 3) {
            const float w0 = (gi == 0) ? w : 0.f;
            const float w1 = (gi == 1) ? w : 0.f;
            const float w2 = (gi == 2) ? w : 0.f;
#define ACC2(u, j0) { \
            float vlo = __uint_as_float((u) << 16); \
            float vhi = __uint_as_float((u) & 0xFFFF0000u); \
            a0[j0] += vlo * w0; a1[j0] += vlo * w1; a2[j0] += vlo * w2; \
            a0[j0+1] += vhi * w0; a1[j0+1] += vhi * w1; a2[j0+1] += vhi * w2; }
            ACC2(h0.x, 0) ACC2(h0.y, 2) ACC2(h0.z, 4) ACC2(h0.w, 6)
            ACC2(h1.x, 8) ACC2(h1.y, 10) ACC2(h1.z, 12) ACC2(h1.w, 14)
#undef ACC2
        } else {
            const unsigned hw[8] = {h0.x, h0.y, h0.z, h0.w, h1.x, h1.y, h1.z, h1.w};
            if (gi < 16) {
#pragma unroll
                for (int q = 0; q < 8; ++q) {
                    atomicAdd(&lhist[gi * 16 + 2 * q],     __uint_as_float(hw[q] << 16) * w);
                    atomicAdd(&lhist[gi * 16 + 2 * q + 1], __uint_as_float(hw[q] & 0xFFFF0000u) * w);
                }
            } else if (gf + gi < G) {
#pragma unroll
                for (int q = 0; q < 8; ++q) {
                    unsafeAtomicAdd(&outagg[(gf + gi) * 16 + 2 * q],     __uint_as_float(hw[q] << 16) * w);
                    unsafeAtomicAdd(&outagg[(gf + gi) * 16 + 2 * q + 1], __uint_as_float(hw[q] & 0xFFFF0000u) * w);
                }
            }
        }
    }

#pragma unroll
    for (int j = 0; j < 16; ++j) {
#pragma unroll
        for (int off = 32; off > 0; off >>= 1) {
            a0[j] += __shfl_down(a0[j], off, 64);
            a1[j] += __shfl_down(a1[j], off, 64);
            a2[j] += __shfl_down(a2[j], off, 64);
        }
    }
    const int wid = t >> 6, lane = t & 63;
    if (lane == 0) {
#pragma unroll
        for (int j = 0; j < 16; ++j) {
            wred[wid * 48 + j]      = a0[j];
            wred[wid * 48 + 16 + j] = a1[j];
            wred[wid * 48 + 32 + j] = a2[j];
        }
    }
    __syncthreads();
    if (t < 48) {
        const float v = wred[t] + wred[48 + t] + wred[96 + t] + wred[144 + t];
        const int g = gf + t / 16;
        if (v != 0.f && g < G) unsafeAtomicAdd(&outagg[g * 16 + (t & 15)], v);
    } else {
        const float v = lhist[t];
        const int g = gf + t / 16;
        if (v != 0.f && g < G) unsafeAtomicAdd(&outagg[g * 16 + (t & 15)], v);
    }
}

// ---------------- final: gcnt via binary search (seg sorted) ----------------
__global__ void k_final(const float* __restrict__ outagg, const int* __restrict__ seg,
                        const float* __restrict__ bias, float* __restrict__ out,
                        int N, int G) {
    int i = blockIdx.x * 256 + threadIdx.x;
    if (i < G * 16) {
        const int g = i >> 4;
        int lo = 0, hi = N;
        while (lo < hi) { int md = (lo + hi) >> 1; if (seg[md] < g) lo = md + 1; else hi = md; }
        const int a = lo; hi = N;
        while (lo < hi) { int md = (lo + hi) >> 1; if (seg[md] <= g) lo = md + 1; else hi = md; }
        const float cnt = (float)(lo - a);
        out[i] = outagg[i] / fmaxf(cnt, 1.f) + bias[i & 15];
    }
}

extern "C" void kernel_launch(void* const* d_in, const int* in_sizes, int n_in,
                              void* d_out, int out_size, void* d_ws, size_t ws_size,
                              hipStream_t stream) {
    const float* X  = (const float*)d_in[0];
    const float* W  = (const float*)d_in[1];
    const float* bb = (const float*)d_in[2];
    const int* esrc = (const int*)d_in[3];
    const int* edst = (const int*)d_in[4];
    const int* seg  = (const int*)d_in[5];
    const int N = in_sizes[5];                 // 100000
    const int E = in_sizes[3];                 // 3200000
    const int G = out_size / 16;               // 256
    const int NBK = (N + 255) >> 8;            // 391 (<=512 required)
    const int NBC = (((E + EVB - 1) / EVB) + 7) & ~7;   // 736 (x8 for swizzle)
    const int Ntab = NBK * NBC;                // 287776 (dst only)
    const int NBsc = (Ntab + 2047) / 2048;     // 141 scan blocks
    const int NT = (N + 15) / 16;              // 6250 MFMA row-tiles

    // ws layout (~19 MB)
    unsigned* drecs = (unsigned*)d_ws;                       // E u32 (12.8 MB)
    int* tab        = (int*)(drecs + (size_t)E);             // Ntab+1 ints (1.15 MB)
    int* bsum       = tab + (Ntab + 1);                      // NBsc (<=1024)
    float* nd       = (float*)(bsum + 1024);                 // N
    float* ns       = nd + N;                                // N
    float* outagg   = ns + N;                                // G*16  <- memset
    unsigned* odeg  = (unsigned*)(outagg + (size_t)G * 16);  // N  <- memset
    unsigned* ideg  = odeg + N;                              // N  <- memset (contig)
    unsigned short* Hb = (unsigned short*)(ideg + N);        // N*16 bf16 (3.2 MB)

    hipMemsetAsync(outagg, 0, (size_t)G * 16 * 4, stream);
    hipMemsetAsync(odeg, 0, (size_t)2 * N * 4, stream);

    k_count  <<<NBC, CTH, 0, stream>>>(esrc, edst, tab, odeg, ideg, E, NBK, NBC);
    k_scanA  <<<NBsc, 256, 0, stream>>>(tab, bsum, Ntab);
    k_scanB  <<<1, 256, 0, stream>>>(bsum, NBsc);
    k_scanC  <<<NBsc, 256, 0, stream>>>(tab, bsum, Ntab);
    k_scatter<<<NBC, CTH, 0, stream>>>(esrc, edst, tab, drecs, E, NBK, NBC);
    k_norm   <<<(N + 255) / 256, 256, 0, stream>>>(odeg, ideg, ns, nd, N);
    k_gemm   <<<512, 256, 0, stream>>>(X, W, ns, Hb, N, NT);
    k_gaccum <<<NBK * 2, 256, 0, stream>>>(drecs, tab, seg, nd, Hb, outagg, N, NBK, NBC, E, G);
    k_final  <<<(G * 16 + 255) / 256, 256, 0, stream>>>(outagg, seg, bb, (float*)d_out, N, G);
}

// Round 6
// 310.659 us; speedup vs baseline: 1.6527x; 1.6527x over previous
//
#include <hip/hip_runtime.h>

#define KMAX 17            // edges per thread in count
#define CTH  256           // threads per count/scatter block
#define EVB  (KMAX * CTH)  // 4352 events per block

typedef __attribute__((ext_vector_type(8))) short short8;
typedef __attribute__((ext_vector_type(4))) float f32x4;

__device__ __forceinline__ unsigned short f2bf(float x) {   // RNE
    unsigned u = __float_as_uint(x);
    u += 0x7FFF + ((u >> 16) & 1);
    return (unsigned short)(u >> 16);
}

__device__ __forceinline__ void gld_lds16(const float* g, float* l) {
    __builtin_amdgcn_global_load_lds(
        (const __attribute__((address_space(1))) unsigned*)g,
        (__attribute__((address_space(3))) unsigned*)l, 16, 0, 0);
}

// ---------------- count events per (bucket, block) ----------------
__global__ __launch_bounds__(CTH) void k_count(const int* __restrict__ src,
        const int* __restrict__ dst, int* __restrict__ tab,
        int E, int NBK, int NBC) {
    __shared__ int cS[512], cD[512];
    const int t = threadIdx.x;
    for (int i = t; i < 512; i += CTH) { cS[i] = 0; cD[i] = 0; }
    __syncthreads();
    const int e0 = blockIdx.x * EVB;
    int e1 = e0 + EVB; if (e1 > E) e1 = E;
    for (int e = e0 + t; e < e1; e += CTH) {
        atomicAdd(&cS[src[e] >> 8], 1);
        atomicAdd(&cD[dst[e] >> 8], 1);
    }
    __syncthreads();
    const int col = (blockIdx.x & 7) * (NBC >> 3) + (blockIdx.x >> 3);
    for (int b = t; b < NBK; b += CTH) {
        tab[(size_t)b * NBC + col]         = cS[b];
        tab[(size_t)(NBK + b) * NBC + col] = cD[b];
    }
}

// ---------------- hierarchical exclusive scan (3 phases) ----------------
__global__ __launch_bounds__(256) void k_scanA(const int* __restrict__ tab,
                                               int* __restrict__ bsum, int Ntab) {
    __shared__ int red[256];
    const int t = threadIdx.x;
    const int base = blockIdx.x * 2048 + t * 8;
    int s = 0;
#pragma unroll
    for (int k = 0; k < 8; ++k) { int i = base + k; if (i < Ntab) s += tab[i]; }
    red[t] = s; __syncthreads();
    for (int off = 128; off > 0; off >>= 1) {
        if (t < off) red[t] += red[t + off];
        __syncthreads();
    }
    if (t == 0) bsum[blockIdx.x] = red[0];
}

__global__ __launch_bounds__(256) void k_scanB(int* __restrict__ bsum, int NB) {
    __shared__ int sc[256];
    __shared__ int carry;
    const int t = threadIdx.x;
    if (t == 0) carry = 0;
    __syncthreads();
    for (int base = 0; base < NB; base += 256) {
        const int i = base + t;
        const int v = (i < NB) ? bsum[i] : 0;
        sc[t] = v; __syncthreads();
        for (int off = 1; off < 256; off <<= 1) {
            int add = (t >= off) ? sc[t - off] : 0;
            __syncthreads();
            sc[t] += add;
            __syncthreads();
        }
        if (i < NB) bsum[i] = carry + sc[t] - v;   // exclusive
        __syncthreads();
        if (t == 255) carry += sc[255];
        __syncthreads();
    }
}

__global__ __launch_bounds__(256) void k_scanC(int* __restrict__ tab,
                                               const int* __restrict__ bsum, int Ntab) {
    __shared__ int sc[256];
    const int t = threadIdx.x;
    const int base = blockIdx.x * 2048 + t * 8;
    int v[8]; int s = 0;
#pragma unroll
    for (int k = 0; k < 8; ++k) { int i = base + k; v[k] = (i < Ntab) ? tab[i] : 0; s += v[k]; }
    sc[t] = s; __syncthreads();
    for (int off = 1; off < 256; off <<= 1) {
        int add = (t >= off) ? sc[t - off] : 0;
        __syncthreads();
        sc[t] += add;
        __syncthreads();
    }
    int run = bsum[blockIdx.x] + sc[t] - s;
#pragma unroll
    for (int k = 0; k < 8; ++k) {
        int i = base + k;
        if (i < Ntab) { tab[i] = run; run += v[k]; }
    }
    if (base < Ntab && Ntab <= base + 8) tab[Ntab] = run;   // sentinel = 2E
}

// ---------------- scatter: DIRECT placement (no stage, no dump) ----------------
// v7: the staged version's prefix scan + 12.8M stage LDS ops + 58M
// binary-search LDS reads existed only to slot->bucket-convert for a dump
// whose useful coalesced runs are ~11-44B anyway. Direct: LDS counters
// preloaded with each bucket's global base (from tab), one LDS atomicAdd
// per record gives the final position; write srecs/drecs straight there.
// Within-segment order is atomic-race order - same nondeterminism as the
// staged version's placement pass; k_degA/k_gaccum are order-insensitive.
__global__ __launch_bounds__(CTH) void k_scatter(const int* __restrict__ src,
        const int* __restrict__ dst, const int* __restrict__ tab,
        unsigned char* __restrict__ srecs, unsigned* __restrict__ drecs,
        int E, int NBK, int NBC) {
    __shared__ int pS[512], pD[512];
    const int t = threadIdx.x;
    const int col = (blockIdx.x & 7) * (NBC >> 3) + (blockIdx.x >> 3);
    for (int b = t; b < NBK; b += CTH) {
        pS[b] = tab[(size_t)b * NBC + col];
        pD[b] = tab[(size_t)(NBK + b) * NBC + col] - E;
    }
    __syncthreads();
    const int e0 = blockIdx.x * EVB;
    int e1 = e0 + EVB; if (e1 > E) e1 = E;
    for (int e = e0 + t; e < e1; e += CTH) {
        const int s = src[e], d = dst[e];
        const int rs = atomicAdd(&pS[s >> 8], 1);
        srecs[rs] = (unsigned char)(s & 255);
        const int rd = atomicAdd(&pD[d >> 8], 1);
        drecs[rd] = ((unsigned)s << 8) | (unsigned)(d & 255);
    }
}

// ---------------- partial degree counts: 4 sub-blocks per bucket ----------------
__global__ __launch_bounds__(256) void k_degA(const unsigned char* __restrict__ srecs,
        const unsigned* __restrict__ drecs, const int* __restrict__ tab,
        unsigned* __restrict__ pdeg, int NBK, int NBC, int E) {
    __shared__ int oc[256], ic[256];
    const int b = blockIdx.x >> 2, s = blockIdx.x & 3;
    const int t = threadIdx.x;
    oc[t] = 0; ic[t] = 0;
    __syncthreads();
    const int sA0 = tab[(size_t)b * NBC];
    const int sA1 = tab[(size_t)(b + 1) * NBC];
    const int dA0 = tab[(size_t)(NBK + b) * NBC] - E;
    const int dA1 = tab[(size_t)(NBK + b + 1) * NBC] - E;
    const int sl = sA1 - sA0, dl = dA1 - dA0;
    const int s0 = sA0 + (sl * s) / 4, s1 = sA0 + (sl * (s + 1)) / 4;
    const int d0 = dA0 + (dl * s) / 4, d1 = dA0 + (dl * (s + 1)) / 4;
    for (int i = s0 + t; i < s1; i += 256) atomicAdd(&oc[srecs[i]], 1);
    for (int i = d0 + t; i < d1; i += 256) atomicAdd(&ic[drecs[i] & 255], 1);
    __syncthreads();
    pdeg[(size_t)blockIdx.x * 256 + t] = (unsigned)oc[t] | ((unsigned)ic[t] << 16);
}

// ---------------- fold partial degrees -> per-node norms ----------------
__global__ __launch_bounds__(256) void k_norm(const unsigned* __restrict__ pdeg,
        float* __restrict__ ns, float* __restrict__ nd, int N) {
    const int node = blockIdx.x * 256 + threadIdx.x;
    if (node >= N) return;
    const int bk = node >> 8, w = node & 255;
    int od = 0, idg = 0;
#pragma unroll
    for (int s = 0; s < 4; ++s) {
        const unsigned p = pdeg[(size_t)(bk * 4 + s) * 256 + w];
        od  += (int)(p & 0xFFFFu);
        idg += (int)(p >> 16);
    }
    ns[node] = rsqrtf(fmaxf((float)od, 1.f));
    nd[node] = rsqrtf(fmaxf((float)idg, 1.f));
}

// ---------------- projection via MFMA (2-term bf16 split) ----------------
// X@W on the matrix pipe. W = Wh+Wl, X = Xh+Xl; XhWh + XhWl + XlWh.
// W fragments in 64 VGPR/lane loaded once; X staged wave-privately via
// global_load_lds (one instr = one contiguous 1KB row), no barriers, next
// tile prefetched under the epilogue. C/D: col=lane&15, row=(lane>>4)*4+reg.
// v7: 2-wave blocks (128 thr, 32KB LDS) -> 5 blocks/CU -> 10 waves/CU
// (was 2 blocks x 4 waves = 8/CU); same 2048 total waves.
__global__ __launch_bounds__(128) void k_gemm(const float* __restrict__ X,
        const float* __restrict__ W, const float* __restrict__ ns,
        unsigned short* __restrict__ Hb, int N, int NT) {
    __shared__ float lx[2][16][256];           // 32 KB, 16 KB per wave
    const int t = threadIdx.x;
    const int wv = t >> 6, l = t & 63;
    const int c = l & 15, g = l >> 4;
    float* myx = &lx[wv][0][0];

    // ---- W fragments, once per wave: slot (kc,g,j) = W[kc*32+g*8+j][c] ----
    short8 wh[8], wl[8];
#pragma unroll
    for (int kc = 0; kc < 8; ++kc) {
#pragma unroll
        for (int j = 0; j < 8; ++j) {
            const float w = W[(kc * 32 + g * 8 + j) * 16 + c];
            const unsigned u = __float_as_uint(w);
            const unsigned short h = (unsigned short)(u >> 16);     // truncate
            const float hf = __uint_as_float((unsigned)h << 16);
            wh[kc][j] = (short)h;
            wl[kc][j] = (short)f2bf(w - hf);
        }
    }

    const int wgid = blockIdx.x * 2 + wv;
    const int wstr = gridDim.x * 2;

    int tile = wgid;
    if (tile < NT) {                           // prologue stage
        const int r0 = tile * 16;
#pragma unroll
        for (int r = 0; r < 16; ++r) {
            const int row = r0 + r;
            if (row < N)
                gld_lds16((const float*)((const char*)&X[(size_t)row * 256]
                           + ((l * 16) ^ ((r & 7) << 4))), &myx[r * 256]);
        }
    }

    for (; tile < NT; tile += wstr) {
        asm volatile("s_waitcnt vmcnt(0)" ::: "memory");
        __builtin_amdgcn_sched_barrier(0);

        const int sig = (c & 7) << 4;          // this lane's A-row swizzle
        const char* base = (const char*)&myx[c * 256];
        f32x4 acc = {0.f, 0.f, 0.f, 0.f};
#pragma unroll
        for (int kc = 0; kc < 8; ++kc) {
            const float4 xa = *(const float4*)(base + kc * 128 + ((g * 32) ^ sig));
            const float4 xb = *(const float4*)(base + kc * 128 + ((g * 32 + 16) ^ sig));
            const float xs[8] = {xa.x, xa.y, xa.z, xa.w, xb.x, xb.y, xb.z, xb.w};
            short8 ah, al;
#pragma unroll
            for (int j = 0; j < 8; ++j) {
                const unsigned u = __float_as_uint(xs[j]);
                const unsigned short h = (unsigned short)(u >> 16);
                const float hf = __uint_as_float((unsigned)h << 16);
                ah[j] = (short)h;
                al[j] = (short)f2bf(xs[j] - hf);
            }
            acc = __builtin_amdgcn_mfma_f32_16x16x32_bf16(ah, wh[kc], acc, 0, 0, 0);
            acc = __builtin_amdgcn_mfma_f32_16x16x32_bf16(ah, wl[kc], acc, 0, 0, 0);
            acc = __builtin_amdgcn_mfma_f32_16x16x32_bf16(al, wh[kc], acc, 0, 0, 0);
        }

        const int nt2 = tile + wstr;           // prefetch next tile under epilogue
        if (nt2 < NT) {
            const int r0 = nt2 * 16;
#pragma unroll
            for (int r = 0; r < 16; ++r) {
                const int row = r0 + r;
                if (row < N)
                    gld_lds16((const float*)((const char*)&X[(size_t)row * 256]
                               + ((l * 16) ^ ((r & 7) << 4))), &myx[r * 256]);
            }
        }

        // epilogue: C/D row = g*4 + v, col = c
        const int rowb = tile * 16 + g * 4;
#pragma unroll
        for (int v = 0; v < 4; ++v) {
            const int row = rowb + v;
            if (row < N)
                Hb[(size_t)row * 16 + c] = f2bf(acc[v] * ns[row]);
        }
    }
}

// ---------------- per-bucket edge accumulation in REGISTERS ----------------
__global__ __launch_bounds__(256) void k_gaccum(const unsigned* __restrict__ drecs,
        const int* __restrict__ tab, const int* __restrict__ seg,
        const float* __restrict__ nd, const unsigned short* __restrict__ Hb,
        float* __restrict__ outagg, int N, int NBK, int NBC, int E, int G) {
    __shared__ float lnd[256];
    __shared__ int   lgi[256];
    __shared__ float lhist[256];
    __shared__ float wred[4 * 48];
    const int b = blockIdx.x >> 1, half = blockIdx.x & 1;
    const int t = threadIdx.x;
    const int node0 = b << 8;
    const int gf = seg[node0];
    lhist[t] = 0.f;
    const int node = node0 + t;
    if (node < N) {
        lnd[t] = nd[node];
        lgi[t] = seg[node] - gf;
    }
    __syncthreads();
    const int dA0 = tab[(size_t)(NBK + b) * NBC] - E;
    const int dA1 = tab[(size_t)(NBK + b + 1) * NBC] - E;
    const int mid = dA0 + ((dA1 - dA0) >> 1);
    const int i0 = half ? mid : dA0;
    const int i1 = half ? dA1 : mid;

    float a0[16], a1[16], a2[16];
#pragma unroll
    for (int j = 0; j < 16; ++j) { a0[j] = 0.f; a1[j] = 0.f; a2[j] = 0.f; }

    for (int i = i0 + t; i < i1; i += 256) {
        const unsigned r = drecs[i];
        const int dlow = r & 255;
        const int s = (int)(r >> 8);
        const float w = lnd[dlow];
        const int gi = lgi[dlow];
        const uint4* hp = (const uint4*)(Hb + (size_t)s * 16);
        const uint4 h0 = hp[0];
        const uint4 h1 = hp[1];
        if (gi < 3) {
            const float w0 = (gi == 0) ? w : 0.f;
            const float w1 = (gi == 1) ? w : 0.f;
            const float w2 = (gi == 2) ? w : 0.f;
#define ACC2(u, j0) { \
            float vlo = __uint_as_float((u) << 16); \
            float vhi = __uint_as_float((u) & 0xFFFF0000u); \
            a0[j0] += vlo * w0; a1[j0] += vlo * w1; a2[j0] += vlo * w2; \
            a0[j0+1] += vhi * w0; a1[j0+1] += vhi * w1; a2[j0+1] += vhi * w2; }
            ACC2(h0.x, 0) ACC2(h0.y, 2) ACC2(h0.z, 4) ACC2(h0.w, 6)
            ACC2(h1.x, 8) ACC2(h1.y, 10) ACC2(h1.z, 12) ACC2(h1.w, 14)
#undef ACC2
        } else {
            const unsigned hw[8] = {h0.x, h0.y, h0.z, h0.w, h1.x, h1.y, h1.z, h1.w};
            if (gi < 16) {
#pragma unroll
                for (int q = 0; q < 8; ++q) {
                    atomicAdd(&lhist[gi * 16 + 2 * q],     __uint_as_float(hw[q] << 16) * w);
                    atomicAdd(&lhist[gi * 16 + 2 * q + 1], __uint_as_float(hw[q] & 0xFFFF0000u) * w);
                }
            } else if (gf + gi < G) {
#pragma unroll
                for (int q = 0; q < 8; ++q) {
                    unsafeAtomicAdd(&outagg[(gf + gi) * 16 + 2 * q],     __uint_as_float(hw[q] << 16) * w);
                    unsafeAtomicAdd(&outagg[(gf + gi) * 16 + 2 * q + 1], __uint_as_float(hw[q] & 0xFFFF0000u) * w);
                }
            }
        }
    }

#pragma unroll
    for (int j = 0; j < 16; ++j) {
#pragma unroll
        for (int off = 32; off > 0; off >>= 1) {
            a0[j] += __shfl_down(a0[j], off, 64);
            a1[j] += __shfl_down(a1[j], off, 64);
            a2[j] += __shfl_down(a2[j], off, 64);
        }
    }
    const int wid = t >> 6, lane = t & 63;
    if (lane == 0) {
#pragma unroll
        for (int j = 0; j < 16; ++j) {
            wred[wid * 48 + j]      = a0[j];
            wred[wid * 48 + 16 + j] = a1[j];
            wred[wid * 48 + 32 + j] = a2[j];
        }
    }
    __syncthreads();
    if (t < 48) {
        const float v = wred[t] + wred[48 + t] + wred[96 + t] + wred[144 + t];
        const int g = gf + t / 16;
        if (v != 0.f && g < G) unsafeAtomicAdd(&outagg[g * 16 + (t & 15)], v);
    } else {
        const float v = lhist[t];
        const int g = gf + t / 16;
        if (v != 0.f && g < G) unsafeAtomicAdd(&outagg[g * 16 + (t & 15)], v);
    }
}

// ---------------- final: gcnt via binary search (seg sorted) ----------------
__global__ void k_final(const float* __restrict__ outagg, const int* __restrict__ seg,
                        const float* __restrict__ bias, float* __restrict__ out,
                        int N, int G) {
    int i = blockIdx.x * 256 + threadIdx.x;
    if (i < G * 16) {
        const int g = i >> 4;
        int lo = 0, hi = N;
        while (lo < hi) { int md = (lo + hi) >> 1; if (seg[md] < g) lo = md + 1; else hi = md; }
        const int a = lo; hi = N;
        while (lo < hi) { int md = (lo + hi) >> 1; if (seg[md] <= g) lo = md + 1; else hi = md; }
        const float cnt = (float)(lo - a);
        out[i] = outagg[i] / fmaxf(cnt, 1.f) + bias[i & 15];
    }
}

extern "C" void kernel_launch(void* const* d_in, const int* in_sizes, int n_in,
                              void* d_out, int out_size, void* d_ws, size_t ws_size,
                              hipStream_t stream) {
    const float* X  = (const float*)d_in[0];
    const float* W  = (const float*)d_in[1];
    const float* bb = (const float*)d_in[2];
    const int* esrc = (const int*)d_in[3];
    const int* edst = (const int*)d_in[4];
    const int* seg  = (const int*)d_in[5];
    const int N = in_sizes[5];                 // 100000
    const int E = in_sizes[3];                 // 3200000
    const int G = out_size / 16;               // 256
    const int NBK = (N + 255) >> 8;            // 391 (<=512 required)
    const int NBC = (((E + EVB - 1) / EVB) + 7) & ~7;   // 736 (x8 for swizzle)
    const int Ntab = 2 * NBK * NBC;            // 575552
    const int NBsc = (Ntab + 2047) / 2048;     // 282 scan blocks
    const int NT = (N + 15) / 16;              // 6250 MFMA row-tiles

    // ws layout (~20.7 MB; srecs/Hb aliased — srecs dead after k_degA)
    unsigned* drecs = (unsigned*)d_ws;                       // E u32 (12.8 MB)
    int* tab        = (int*)(drecs + (size_t)E);             // Ntab+1 ints (2.3 MB)
    int* bsum       = tab + (Ntab + 1);                      // NBsc (<=1024)
    float* nd       = (float*)(bsum + 1024);                 // N
    float* ns       = nd + N;                                // N
    float* outagg   = ns + N;                                // G*16  <- memset
    unsigned* pdeg  = (unsigned*)(outagg + (size_t)G * 16);  // NBK*4*256 (1.6 MB)
    unsigned char* srecs = (unsigned char*)(pdeg + (size_t)NBK * 4 * 256); // E bytes \ alias
    unsigned short* Hb   = (unsigned short*)srecs;                          // N*16   / region

    hipMemsetAsync(outagg, 0, (size_t)G * 16 * 4, stream);

    k_count  <<<NBC, CTH, 0, stream>>>(esrc, edst, tab, E, NBK, NBC);
    k_scanA  <<<NBsc, 256, 0, stream>>>(tab, bsum, Ntab);
    k_scanB  <<<1, 256, 0, stream>>>(bsum, NBsc);
    k_scanC  <<<NBsc, 256, 0, stream>>>(tab, bsum, Ntab);
    k_scatter<<<NBC, CTH, 0, stream>>>(esrc, edst, tab, srecs, drecs, E, NBK, NBC);
    k_degA   <<<NBK * 4, 256, 0, stream>>>(srecs, drecs, tab, pdeg, NBK, NBC, E);
    k_norm   <<<(N + 255) / 256, 256, 0, stream>>>(pdeg, ns, nd, N);
    k_gemm   <<<1024, 128, 0, stream>>>(X, W, ns, Hb, N, NT);
    k_gaccum <<<NBK * 2, 256, 0, stream>>>(drecs, tab, seg, nd, Hb, outagg, N, NBK, NBC, E, G);
    k_final  <<<(G * 16 + 255) / 256, 256, 0, stream>>>(outagg, seg, bb, (float*)d_out, N, G);
}

// Round 7
// 307.901 us; speedup vs baseline: 1.6675x; 1.0090x over previous
//
#include <hip/hip_runtime.h>

#define KMAX 17            // edges per thread in count
#define CTH  256           // threads per count/scatter block
#define EVB  (KMAX * CTH)  // 4352 events per block

typedef __attribute__((ext_vector_type(8))) short short8;
typedef __attribute__((ext_vector_type(4))) float f32x4;

__device__ __forceinline__ unsigned short f2bf(float x) {   // RNE
    unsigned u = __float_as_uint(x);
    u += 0x7FFF + ((u >> 16) & 1);
    return (unsigned short)(u >> 16);
}

__device__ __forceinline__ void gld_lds16(const float* g, float* l) {
    __builtin_amdgcn_global_load_lds(
        (const __attribute__((address_space(1))) unsigned*)g,
        (__attribute__((address_space(3))) unsigned*)l, 16, 0, 0);
}

// ---------------- count events per (bucket, block); block 0 zeroes outagg ----
__global__ __launch_bounds__(CTH) void k_count(const int* __restrict__ src,
        const int* __restrict__ dst, int* __restrict__ tab,
        float* __restrict__ outagg, int E, int NBK, int NBC, int G) {
    __shared__ int cS[512], cD[512];
    const int t = threadIdx.x;
    for (int i = t; i < 512; i += CTH) { cS[i] = 0; cD[i] = 0; }
    if (blockIdx.x == 0)                       // replaces hipMemsetAsync
        for (int i = t; i < G * 16; i += CTH) outagg[i] = 0.f;
    __syncthreads();
    const int e0 = blockIdx.x * EVB;
    int e1 = e0 + EVB; if (e1 > E) e1 = E;
    for (int e = e0 + t; e < e1; e += CTH) {
        atomicAdd(&cS[src[e] >> 8], 1);
        atomicAdd(&cD[dst[e] >> 8], 1);
    }
    __syncthreads();
    const int col = (blockIdx.x & 7) * (NBC >> 3) + (blockIdx.x >> 3);
    for (int b = t; b < NBK; b += CTH) {
        tab[(size_t)b * NBC + col]         = cS[b];
        tab[(size_t)(NBK + b) * NBC + col] = cD[b];
    }
}

// ---------------- hierarchical exclusive scan (2 dispatches) ----------------
__global__ __launch_bounds__(256) void k_scanA(const int* __restrict__ tab,
                                               int* __restrict__ bsum, int Ntab) {
    __shared__ int red[256];
    const int t = threadIdx.x;
    const int base = blockIdx.x * 2048 + t * 8;
    int s = 0;
#pragma unroll
    for (int k = 0; k < 8; ++k) { int i = base + k; if (i < Ntab) s += tab[i]; }
    red[t] = s; __syncthreads();
    for (int off = 128; off > 0; off >>= 1) {
        if (t < off) red[t] += red[t + off];
        __syncthreads();
    }
    if (t == 0) bsum[blockIdx.x] = red[0];
}

// scanC now computes its own bsum prefix (scanB folded in: each block
// redundantly reduces the <=1024-entry bsum slice it needs; ~1KB read).
__global__ __launch_bounds__(256) void k_scanC(int* __restrict__ tab,
                                               const int* __restrict__ bsum,
                                               int Ntab, int NB) {
    __shared__ int sc[256];
    __shared__ int red[256];
    const int t = threadIdx.x;
    // blockBase = sum of bsum[j], j < blockIdx.x
    int p = 0;
    for (int j = t; j < NB; j += 256)
        if (j < blockIdx.x) p += bsum[j];
    red[t] = p; __syncthreads();
    for (int off = 128; off > 0; off >>= 1) {
        if (t < off) red[t] += red[t + off];
        __syncthreads();
    }
    const int blockBase = red[0];

    const int base = blockIdx.x * 2048 + t * 8;
    int v[8]; int s = 0;
#pragma unroll
    for (int k = 0; k < 8; ++k) { int i = base + k; v[k] = (i < Ntab) ? tab[i] : 0; s += v[k]; }
    sc[t] = s; __syncthreads();
    for (int off = 1; off < 256; off <<= 1) {
        int add = (t >= off) ? sc[t - off] : 0;
        __syncthreads();
        sc[t] += add;
        __syncthreads();
    }
    int run = blockBase + sc[t] - s;
#pragma unroll
    for (int k = 0; k < 8; ++k) {
        int i = base + k;
        if (i < Ntab) { tab[i] = run; run += v[k]; }
    }
    if (base < Ntab && Ntab <= base + 8) tab[Ntab] = run;   // sentinel = 2E
}

// ---------------- scatter: DIRECT placement (unchanged from r6) ----------------
__global__ __launch_bounds__(CTH) void k_scatter(const int* __restrict__ src,
        const int* __restrict__ dst, const int* __restrict__ tab,
        unsigned char* __restrict__ srecs, unsigned* __restrict__ drecs,
        int E, int NBK, int NBC) {
    __shared__ int pS[512], pD[512];
    const int t = threadIdx.x;
    const int col = (blockIdx.x & 7) * (NBC >> 3) + (blockIdx.x >> 3);
    for (int b = t; b < NBK; b += CTH) {
        pS[b] = tab[(size_t)b * NBC + col];
        pD[b] = tab[(size_t)(NBK + b) * NBC + col] - E;
    }
    __syncthreads();
    const int e0 = blockIdx.x * EVB;
    int e1 = e0 + EVB; if (e1 > E) e1 = E;
    for (int e = e0 + t; e < e1; e += CTH) {
        const int s = src[e], d = dst[e];
        const int rs = atomicAdd(&pS[s >> 8], 1);
        srecs[rs] = (unsigned char)(s & 255);
        const int rd = atomicAdd(&pD[d >> 8], 1);
        drecs[rd] = ((unsigned)s << 8) | (unsigned)(d & 255);
    }
}

// ---------------- degrees + norms: one block per bucket (degA+norm fused) ----
__global__ __launch_bounds__(256) void k_degnorm(const unsigned char* __restrict__ srecs,
        const unsigned* __restrict__ drecs, const int* __restrict__ tab,
        float* __restrict__ ns, float* __restrict__ nd,
        int NBK, int NBC, int E, int N) {
    __shared__ int oc[256], ic[256];
    const int b = blockIdx.x;
    const int t = threadIdx.x;
    oc[t] = 0; ic[t] = 0;
    __syncthreads();
    const int sA0 = tab[(size_t)b * NBC];
    const int sA1 = tab[(size_t)(b + 1) * NBC];
    const int dA0 = tab[(size_t)(NBK + b) * NBC] - E;
    const int dA1 = tab[(size_t)(NBK + b + 1) * NBC] - E;   // b=NBK-1 hits sentinel
    for (int i = sA0 + t; i < sA1; i += 256) atomicAdd(&oc[srecs[i]], 1);
    for (int i = dA0 + t; i < dA1; i += 256) atomicAdd(&ic[drecs[i] & 255], 1);
    __syncthreads();
    const int node = (b << 8) + t;
    if (node < N) {
        ns[node] = rsqrtf(fmaxf((float)oc[t], 1.f));
        nd[node] = rsqrtf(fmaxf((float)ic[t], 1.f));
    }
}

// ---------------- projection via MFMA (2-term bf16 split; unchanged r6) ------
__global__ __launch_bounds__(128) void k_gemm(const float* __restrict__ X,
        const float* __restrict__ W, const float* __restrict__ ns,
        unsigned short* __restrict__ Hb, int N, int NT) {
    __shared__ float lx[2][16][256];           // 32 KB, 16 KB per wave
    const int t = threadIdx.x;
    const int wv = t >> 6, l = t & 63;
    const int c = l & 15, g = l >> 4;
    float* myx = &lx[wv][0][0];

    short8 wh[8], wl[8];
#pragma unroll
    for (int kc = 0; kc < 8; ++kc) {
#pragma unroll
        for (int j = 0; j < 8; ++j) {
            const float w = W[(kc * 32 + g * 8 + j) * 16 + c];
            const unsigned u = __float_as_uint(w);
            const unsigned short h = (unsigned short)(u >> 16);     // truncate
            const float hf = __uint_as_float((unsigned)h << 16);
            wh[kc][j] = (short)h;
            wl[kc][j] = (short)f2bf(w - hf);
        }
    }

    const int wgid = blockIdx.x * 2 + wv;
    const int wstr = gridDim.x * 2;

    int tile = wgid;
    if (tile < NT) {                           // prologue stage
        const int r0 = tile * 16;
#pragma unroll
        for (int r = 0; r < 16; ++r) {
            const int row = r0 + r;
            if (row < N)
                gld_lds16((const float*)((const char*)&X[(size_t)row * 256]
                           + ((l * 16) ^ ((r & 7) << 4))), &myx[r * 256]);
        }
    }

    for (; tile < NT; tile += wstr) {
        asm volatile("s_waitcnt vmcnt(0)" ::: "memory");
        __builtin_amdgcn_sched_barrier(0);

        const int sig = (c & 7) << 4;          // this lane's A-row swizzle
        const char* base = (const char*)&myx[c * 256];
        f32x4 acc = {0.f, 0.f, 0.f, 0.f};
#pragma unroll
        for (int kc = 0; kc < 8; ++kc) {
            const float4 xa = *(const float4*)(base + kc * 128 + ((g * 32) ^ sig));
            const float4 xb = *(const float4*)(base + kc * 128 + ((g * 32 + 16) ^ sig));
            const float xs[8] = {xa.x, xa.y, xa.z, xa.w, xb.x, xb.y, xb.z, xb.w};
            short8 ah, al;
#pragma unroll
            for (int j = 0; j < 8; ++j) {
                const unsigned u = __float_as_uint(xs[j]);
                const unsigned short h = (unsigned short)(u >> 16);
                const float hf = __uint_as_float((unsigned)h << 16);
                ah[j] = (short)h;
                al[j] = (short)f2bf(xs[j] - hf);
            }
            acc = __builtin_amdgcn_mfma_f32_16x16x32_bf16(ah, wh[kc], acc, 0, 0, 0);
            acc = __builtin_amdgcn_mfma_f32_16x16x32_bf16(ah, wl[kc], acc, 0, 0, 0);
            acc = __builtin_amdgcn_mfma_f32_16x16x32_bf16(al, wh[kc], acc, 0, 0, 0);
        }

        const int nt2 = tile + wstr;           // prefetch next tile under epilogue
        if (nt2 < NT) {
            const int r0 = nt2 * 16;
#pragma unroll
            for (int r = 0; r < 16; ++r) {
                const int row = r0 + r;
                if (row < N)
                    gld_lds16((const float*)((const char*)&X[(size_t)row * 256]
                               + ((l * 16) ^ ((r & 7) << 4))), &myx[r * 256]);
            }
        }

        // epilogue: C/D row = g*4 + v, col = c
        const int rowb = tile * 16 + g * 4;
#pragma unroll
        for (int v = 0; v < 4; ++v) {
            const int row = rowb + v;
            if (row < N)
                Hb[(size_t)row * 16 + c] = f2bf(acc[v] * ns[row]);
        }
    }
}

// ---------------- per-bucket edge accumulation in REGISTERS ----------------
__global__ __launch_bounds__(256) void k_gaccum(const unsigned* __restrict__ drecs,
        const int* __restrict__ tab, const int* __restrict__ seg,
        const float* __restrict__ nd, const unsigned short* __restrict__ Hb,
        float* __restrict__ outagg, int N, int NBK, int NBC, int E, int G) {
    __shared__ float lnd[256];
    __shared__ int   lgi[256];
    __shared__ float lhist[256];
    __shared__ float wred[4 * 48];
    const int b = blockIdx.x >> 1, half = blockIdx.x & 1;
    const int t = threadIdx.x;
    const int node0 = b << 8;
    const int gf = seg[node0];
    lhist[t] = 0.f;
    const int node = node0 + t;
    if (node < N) {
        lnd[t] = nd[node];
        lgi[t] = seg[node] - gf;
    }
    __syncthreads();
    const int dA0 = tab[(size_t)(NBK + b) * NBC] - E;
    const int dA1 = tab[(size_t)(NBK + b + 1) * NBC] - E;
    const int mid = dA0 + ((dA1 - dA0) >> 1);
    const int i0 = half ? mid : dA0;
    const int i1 = half ? dA1 : mid;

    float a0[16], a1[16], a2[16];
#pragma unroll
    for (int j = 0; j < 16; ++j) { a0[j] = 0.f; a1[j] = 0.f; a2[j] = 0.f; }

    for (int i = i0 + t; i < i1; i += 256) {
        const unsigned r = drecs[i];
        const int dlow = r & 255;
        const int s = (int)(r >> 8);
        const float w = lnd[dlow];
        const int gi = lgi[dlow];
        const uint4* hp = (const uint4*)(Hb + (size_t)s * 16);
        const uint4 h0 = hp[0];
        const uint4 h1 = hp[1];
        if (gi < 3) {
            const float w0 = (gi == 0) ? w : 0.f;
            const float w1 = (gi == 1) ? w : 0.f;
            const float w2 = (gi == 2) ? w : 0.f;
#define ACC2(u, j0) { \
            float vlo = __uint_as_float((u) << 16); \
            float vhi = __uint_as_float((u) & 0xFFFF0000u); \
            a0[j0] += vlo * w0; a1[j0] += vlo * w1; a2[j0] += vlo * w2; \
            a0[j0+1] += vhi * w0; a1[j0+1] += vhi * w1; a2[j0+1] += vhi * w2; }
            ACC2(h0.x, 0) ACC2(h0.y, 2) ACC2(h0.z, 4) ACC2(h0.w, 6)
            ACC2(h1.x, 8) ACC2(h1.y, 10) ACC2(h1.z, 12) ACC2(h1.w, 14)
#undef ACC2
        } else {
            const unsigned hw[8] = {h0.x, h0.y, h0.z, h0.w, h1.x, h1.y, h1.z, h1.w};
            if (gi < 16) {
#pragma unroll
                for (int q = 0; q < 8; ++q) {
                    atomicAdd(&lhist[gi * 16 + 2 * q],     __uint_as_float(hw[q] << 16) * w);
                    atomicAdd(&lhist[gi * 16 + 2 * q + 1], __uint_as_float(hw[q] & 0xFFFF0000u) * w);
                }
            } else if (gf + gi < G) {
#pragma unroll
                for (int q = 0; q < 8; ++q) {
                    unsafeAtomicAdd(&outagg[(gf + gi) * 16 + 2 * q],     __uint_as_float(hw[q] << 16) * w);
                    unsafeAtomicAdd(&outagg[(gf + gi) * 16 + 2 * q + 1], __uint_as_float(hw[q] & 0xFFFF0000u) * w);
                }
            }
        }
    }

#pragma unroll
    for (int j = 0; j < 16; ++j) {
#pragma unroll
        for (int off = 32; off > 0; off >>= 1) {
            a0[j] += __shfl_down(a0[j], off, 64);
            a1[j] += __shfl_down(a1[j], off, 64);
            a2[j] += __shfl_down(a2[j], off, 64);
        }
    }
    const int wid = t >> 6, lane = t & 63;
    if (lane == 0) {
#pragma unroll
        for (int j = 0; j < 16; ++j) {
            wred[wid * 48 + j]      = a0[j];
            wred[wid * 48 + 16 + j] = a1[j];
            wred[wid * 48 + 32 + j] = a2[j];
        }
    }
    __syncthreads();
    if (t < 48) {
        const float v = wred[t] + wred[48 + t] + wred[96 + t] + wred[144 + t];
        const int g = gf + t / 16;
        if (v != 0.f && g < G) unsafeAtomicAdd(&outagg[g * 16 + (t & 15)], v);
    } else {
        const float v = lhist[t];
        const int g = gf + t / 16;
        if (v != 0.f && g < G) unsafeAtomicAdd(&outagg[g * 16 + (t & 15)], v);
    }
}

// ---------------- final: gcnt via binary search (seg sorted) ----------------
__global__ void k_final(const float* __restrict__ outagg, const int* __restrict__ seg,
                        const float* __restrict__ bias, float* __restrict__ out,
                        int N, int G) {
    int i = blockIdx.x * 256 + threadIdx.x;
    if (i < G * 16) {
        const int g = i >> 4;
        int lo = 0, hi = N;
        while (lo < hi) { int md = (lo + hi) >> 1; if (seg[md] < g) lo = md + 1; else hi = md; }
        const int a = lo; hi = N;
        while (lo < hi) { int md = (lo + hi) >> 1; if (seg[md] <= g) lo = md + 1; else hi = md; }
        const float cnt = (float)(lo - a);
        out[i] = outagg[i] / fmaxf(cnt, 1.f) + bias[i & 15];
    }
}

extern "C" void kernel_launch(void* const* d_in, const int* in_sizes, int n_in,
                              void* d_out, int out_size, void* d_ws, size_t ws_size,
                              hipStream_t stream) {
    const float* X  = (const float*)d_in[0];
    const float* W  = (const float*)d_in[1];
    const float* bb = (const float*)d_in[2];
    const int* esrc = (const int*)d_in[3];
    const int* edst = (const int*)d_in[4];
    const int* seg  = (const int*)d_in[5];
    const int N = in_sizes[5];                 // 100000
    const int E = in_sizes[3];                 // 3200000
    const int G = out_size / 16;               // 256
    const int NBK = (N + 255) >> 8;            // 391 (<=512 required)
    const int NBC = (((E + EVB - 1) / EVB) + 7) & ~7;   // 736 (x8 for swizzle)
    const int Ntab = 2 * NBK * NBC;            // 575552
    const int NBsc = (Ntab + 2047) / 2048;     // 282 scan blocks
    const int NT = (N + 15) / 16;              // 6250 MFMA row-tiles

    // ws layout (~19 MB; srecs/Hb aliased — srecs dead after k_degnorm)
    unsigned* drecs = (unsigned*)d_ws;                       // E u32 (12.8 MB)
    int* tab        = (int*)(drecs + (size_t)E);             // Ntab+1 ints (2.3 MB)
    int* bsum       = tab + (Ntab + 1);                      // NBsc (<=1024)
    float* nd       = (float*)(bsum + 1024);                 // N
    float* ns       = nd + N;                                // N
    float* outagg   = ns + N;                                // G*16 (zeroed by k_count)
    unsigned char* srecs = (unsigned char*)(outagg + (size_t)G * 16); // E bytes \ alias
    unsigned short* Hb   = (unsigned short*)srecs;                     // N*16    / region

    k_count  <<<NBC, CTH, 0, stream>>>(esrc, edst, tab, outagg, E, NBK, NBC, G);
    k_scanA  <<<NBsc, 256, 0, stream>>>(tab, bsum, Ntab);
    k_scanC  <<<NBsc, 256, 0, stream>>>(tab, bsum, Ntab, NBsc);
    k_scatter<<<NBC, CTH, 0, stream>>>(esrc, edst, tab, srecs, drecs, E, NBK, NBC);
    k_degnorm<<<NBK, 256, 0, stream>>>(srecs, drecs, tab, ns, nd, NBK, NBC, E, N);
    k_gemm   <<<1024, 128, 0, stream>>>(X, W, ns, Hb, N, NT);
    k_gaccum <<<NBK * 2, 256, 0, stream>>>(drecs, tab, seg, nd, Hb, outagg, N, NBK, NBC, E, G);
    k_final  <<<(G * 16 + 255) / 256, 256, 0, stream>>>(outagg, seg, bb, (float*)d_out, N, G);
}

// Round 8
// 299.122 us; speedup vs baseline: 1.7164x; 1.0293x over previous
//
#include <hip/hip_runtime.h>

#define KMAX 17            // edges per thread in scatter
#define CTH  256           // threads per scatter block
#define EVB  (KMAX * CTH)  // 4352 edges per block
#define CAP  9216          // bucket arena capacity (mean 8192, sigma~90 -> 11-sigma margin)

typedef __attribute__((ext_vector_type(8))) short short8;
typedef __attribute__((ext_vector_type(4))) float f32x4;

__device__ __forceinline__ unsigned short f2bf(float x) {   // RNE
    unsigned u = __float_as_uint(x);
    u += 0x7FFF + ((u >> 16) & 1);
    return (unsigned short)(u >> 16);
}

__device__ __forceinline__ void gld_lds16(const float* g, float* l) {
    __builtin_amdgcn_global_load_lds(
        (const __attribute__((address_space(1))) unsigned*)g,
        (__attribute__((address_space(3))) unsigned*)l, 16, 0, 0);
}

// ---------------- scatter: single-pass arena placement ----------------
// v8: buckets live in fixed-CAP arenas, so no global scan is needed and
// src/dst are read ONCE (edges held in registers across count->reserve->
// place). Per block: LDS count per bucket, one global atomicAdd per
// (block,bucket) reserves a chunk (287K atomics, ~736 racers/address),
// LDS cursors place. Final cursor values = bucket lengths for consumers.
// Replaces k_count + k_scanA + k_scanC + staged k_scatter (2 full passes
// over 25.6MB + 6.4M extra LDS atomics + 4.6MB scan traffic deleted).
__global__ __launch_bounds__(CTH) void k_scatter(const int* __restrict__ src,
        const int* __restrict__ dst, unsigned* __restrict__ curS,
        unsigned* __restrict__ curD, unsigned char* __restrict__ srecs,
        unsigned* __restrict__ drecs, float* __restrict__ outagg,
        int E, int NBK, int G) {
    __shared__ int cS[512], cD[512];
    const int t = threadIdx.x;
    for (int i = t; i < 512; i += CTH) { cS[i] = 0; cD[i] = 0; }
    if (blockIdx.x == 0)                       // zero outagg (used by k_gaccum later)
        for (int i = t; i < G * 16; i += CTH) outagg[i] = 0.f;
    __syncthreads();
    const int e0 = blockIdx.x * EVB;
    int e1 = e0 + EVB; if (e1 > E) e1 = E;

    int sv[KMAX], dv[KMAX];
#pragma unroll
    for (int k = 0; k < KMAX; ++k) {
        const int e = e0 + k * CTH + t;
        if (e < e1) {
            sv[k] = src[e]; dv[k] = dst[e];
            atomicAdd(&cS[sv[k] >> 8], 1);
            atomicAdd(&cD[dv[k] >> 8], 1);
        }
    }
    __syncthreads();
    for (int b = t; b < NBK; b += CTH) {       // reserve chunks; reuse cS/cD as cursors
        cS[b] = b * CAP + (int)atomicAdd(&curS[b], (unsigned)cS[b]);
        cD[b] = b * CAP + (int)atomicAdd(&curD[b], (unsigned)cD[b]);
    }
    __syncthreads();
#pragma unroll
    for (int k = 0; k < KMAX; ++k) {
        const int e = e0 + k * CTH + t;
        if (e < e1) {
            const int s = sv[k], d = dv[k];
            const int rs = atomicAdd(&cS[s >> 8], 1);
            srecs[rs] = (unsigned char)(s & 255);
            const int rd = atomicAdd(&cD[d >> 8], 1);
            drecs[rd] = ((unsigned)s << 8) | (unsigned)(d & 255);
        }
    }
}

// ---------------- degrees + norms: 2*NBK blocks (src and dst split) ----------
__global__ __launch_bounds__(256) void k_degnorm(const unsigned char* __restrict__ srecs,
        const unsigned* __restrict__ drecs, const unsigned* __restrict__ curS,
        const unsigned* __restrict__ curD, float* __restrict__ ns,
        float* __restrict__ nd, int NBK, int N) {
    __shared__ int hist[256];
    const int t = threadIdx.x;
    const bool isD = blockIdx.x >= NBK;
    const int b = isD ? blockIdx.x - NBK : blockIdx.x;
    hist[t] = 0;
    __syncthreads();
    const int a0 = b * CAP;
    if (isD) {
        const int a1 = a0 + (int)curD[b];
        for (int i = a0 + t; i < a1; i += 256) atomicAdd(&hist[drecs[i] & 255], 1);
    } else {
        const int a1 = a0 + (int)curS[b];
        for (int i = a0 + t; i < a1; i += 256) atomicAdd(&hist[srecs[i]], 1);
    }
    __syncthreads();
    const int node = (b << 8) + t;
    if (node < N) {
        const float r = rsqrtf(fmaxf((float)hist[t], 1.f));
        if (isD) nd[node] = r; else ns[node] = r;
    }
}

// ---------------- projection via MFMA (2-term bf16 split; unchanged) ---------
__global__ __launch_bounds__(128) void k_gemm(const float* __restrict__ X,
        const float* __restrict__ W, const float* __restrict__ ns,
        unsigned short* __restrict__ Hb, int N, int NT) {
    __shared__ float lx[2][16][256];           // 32 KB, 16 KB per wave
    const int t = threadIdx.x;
    const int wv = t >> 6, l = t & 63;
    const int c = l & 15, g = l >> 4;
    float* myx = &lx[wv][0][0];

    short8 wh[8], wl[8];
#pragma unroll
    for (int kc = 0; kc < 8; ++kc) {
#pragma unroll
        for (int j = 0; j < 8; ++j) {
            const float w = W[(kc * 32 + g * 8 + j) * 16 + c];
            const unsigned u = __float_as_uint(w);
            const unsigned short h = (unsigned short)(u >> 16);     // truncate
            const float hf = __uint_as_float((unsigned)h << 16);
            wh[kc][j] = (short)h;
            wl[kc][j] = (short)f2bf(w - hf);
        }
    }

    const int wgid = blockIdx.x * 2 + wv;
    const int wstr = gridDim.x * 2;

    int tile = wgid;
    if (tile < NT) {                           // prologue stage
        const int r0 = tile * 16;
#pragma unroll
        for (int r = 0; r < 16; ++r) {
            const int row = r0 + r;
            if (row < N)
                gld_lds16((const float*)((const char*)&X[(size_t)row * 256]
                           + ((l * 16) ^ ((r & 7) << 4))), &myx[r * 256]);
        }
    }

    for (; tile < NT; tile += wstr) {
        asm volatile("s_waitcnt vmcnt(0)" ::: "memory");
        __builtin_amdgcn_sched_barrier(0);

        const int sig = (c & 7) << 4;          // this lane's A-row swizzle
        const char* base = (const char*)&myx[c * 256];
        f32x4 acc = {0.f, 0.f, 0.f, 0.f};
#pragma unroll
        for (int kc = 0; kc < 8; ++kc) {
            const float4 xa = *(const float4*)(base + kc * 128 + ((g * 32) ^ sig));
            const float4 xb = *(const float4*)(base + kc * 128 + ((g * 32 + 16) ^ sig));
            const float xs[8] = {xa.x, xa.y, xa.z, xa.w, xb.x, xb.y, xb.z, xb.w};
            short8 ah, al;
#pragma unroll
            for (int j = 0; j < 8; ++j) {
                const unsigned u = __float_as_uint(xs[j]);
                const unsigned short h = (unsigned short)(u >> 16);
                const float hf = __uint_as_float((unsigned)h << 16);
                ah[j] = (short)h;
                al[j] = (short)f2bf(xs[j] - hf);
            }
            acc = __builtin_amdgcn_mfma_f32_16x16x32_bf16(ah, wh[kc], acc, 0, 0, 0);
            acc = __builtin_amdgcn_mfma_f32_16x16x32_bf16(ah, wl[kc], acc, 0, 0, 0);
            acc = __builtin_amdgcn_mfma_f32_16x16x32_bf16(al, wh[kc], acc, 0, 0, 0);
        }

        const int nt2 = tile + wstr;           // prefetch next tile under epilogue
        if (nt2 < NT) {
            const int r0 = nt2 * 16;
#pragma unroll
            for (int r = 0; r < 16; ++r) {
                const int row = r0 + r;
                if (row < N)
                    gld_lds16((const float*)((const char*)&X[(size_t)row * 256]
                               + ((l * 16) ^ ((r & 7) << 4))), &myx[r * 256]);
            }
        }

        // epilogue: C/D row = g*4 + v, col = c
        const int rowb = tile * 16 + g * 4;
#pragma unroll
        for (int v = 0; v < 4; ++v) {
            const int row = rowb + v;
            if (row < N)
                Hb[(size_t)row * 16 + c] = f2bf(acc[v] * ns[row]);
        }
    }
}

// ---------------- per-bucket edge accumulation in REGISTERS ----------------
__global__ __launch_bounds__(256) void k_gaccum(const unsigned* __restrict__ drecs,
        const unsigned* __restrict__ curD, const int* __restrict__ seg,
        const float* __restrict__ nd, const unsigned short* __restrict__ Hb,
        float* __restrict__ outagg, int N, int G) {
    __shared__ float lnd[256];
    __shared__ int   lgi[256];
    __shared__ float lhist[256];
    __shared__ float wred[4 * 48];
    const int b = blockIdx.x >> 1, half = blockIdx.x & 1;
    const int t = threadIdx.x;
    const int node0 = b << 8;
    const int gf = seg[node0];
    lhist[t] = 0.f;
    const int node = node0 + t;
    if (node < N) {
        lnd[t] = nd[node];
        lgi[t] = seg[node] - gf;
    }
    __syncthreads();
    const int dA0 = b * CAP;
    const int dA1 = dA0 + (int)curD[b];
    const int mid = dA0 + ((dA1 - dA0) >> 1);
    const int i0 = half ? mid : dA0;
    const int i1 = half ? dA1 : mid;

    float a0[16], a1[16], a2[16];
#pragma unroll
    for (int j = 0; j < 16; ++j) { a0[j] = 0.f; a1[j] = 0.f; a2[j] = 0.f; }

    for (int i = i0 + t; i < i1; i += 256) {
        const unsigned r = drecs[i];
        const int dlow = r & 255;
        const int s = (int)(r >> 8);
        const float w = lnd[dlow];
        const int gi = lgi[dlow];
        const uint4* hp = (const uint4*)(Hb + (size_t)s * 16);
        const uint4 h0 = hp[0];
        const uint4 h1 = hp[1];
        if (gi < 3) {
            const float w0 = (gi == 0) ? w : 0.f;
            const float w1 = (gi == 1) ? w : 0.f;
            const float w2 = (gi == 2) ? w : 0.f;
#define ACC2(u, j0) { \
            float vlo = __uint_as_float((u) << 16); \
            float vhi = __uint_as_float((u) & 0xFFFF0000u); \
            a0[j0] += vlo * w0; a1[j0] += vlo * w1; a2[j0] += vlo * w2; \
            a0[j0+1] += vhi * w0; a1[j0+1] += vhi * w1; a2[j0+1] += vhi * w2; }
            ACC2(h0.x, 0) ACC2(h0.y, 2) ACC2(h0.z, 4) ACC2(h0.w, 6)
            ACC2(h1.x, 8) ACC2(h1.y, 10) ACC2(h1.z, 12) ACC2(h1.w, 14)
#undef ACC2
        } else {
            const unsigned hw[8] = {h0.x, h0.y, h0.z, h0.w, h1.x, h1.y, h1.z, h1.w};
            if (gi < 16) {
#pragma unroll
                for (int q = 0; q < 8; ++q) {
                    atomicAdd(&lhist[gi * 16 + 2 * q],     __uint_as_float(hw[q] << 16) * w);
                    atomicAdd(&lhist[gi * 16 + 2 * q + 1], __uint_as_float(hw[q] & 0xFFFF0000u) * w);
                }
            } else if (gf + gi < G) {
#pragma unroll
                for (int q = 0; q < 8; ++q) {
                    unsafeAtomicAdd(&outagg[(gf + gi) * 16 + 2 * q],     __uint_as_float(hw[q] << 16) * w);
                    unsafeAtomicAdd(&outagg[(gf + gi) * 16 + 2 * q + 1], __uint_as_float(hw[q] & 0xFFFF0000u) * w);
                }
            }
        }
    }

#pragma unroll
    for (int j = 0; j < 16; ++j) {
#pragma unroll
        for (int off = 32; off > 0; off >>= 1) {
            a0[j] += __shfl_down(a0[j], off, 64);
            a1[j] += __shfl_down(a1[j], off, 64);
            a2[j] += __shfl_down(a2[j], off, 64);
        }
    }
    const int wid = t >> 6, lane = t & 63;
    if (lane == 0) {
#pragma unroll
        for (int j = 0; j < 16; ++j) {
            wred[wid * 48 + j]      = a0[j];
            wred[wid * 48 + 16 + j] = a1[j];
            wred[wid * 48 + 32 + j] = a2[j];
        }
    }
    __syncthreads();
    if (t < 48) {
        const float v = wred[t] + wred[48 + t] + wred[96 + t] + wred[144 + t];
        const int g = gf + t / 16;
        if (v != 0.f && g < G) unsafeAtomicAdd(&outagg[g * 16 + (t & 15)], v);
    } else {
        const float v = lhist[t];
        const int g = gf + t / 16;
        if (v != 0.f && g < G) unsafeAtomicAdd(&outagg[g * 16 + (t & 15)], v);
    }
}

// ---------------- final: gcnt via binary search (seg sorted) ----------------
__global__ void k_final(const float* __restrict__ outagg, const int* __restrict__ seg,
                        const float* __restrict__ bias, float* __restrict__ out,
                        int N, int G) {
    int i = blockIdx.x * 256 + threadIdx.x;
    if (i < G * 16) {
        const int g = i >> 4;
        int lo = 0, hi = N;
        while (lo < hi) { int md = (lo + hi) >> 1; if (seg[md] < g) lo = md + 1; else hi = md; }
        const int a = lo; hi = N;
        while (lo < hi) { int md = (lo + hi) >> 1; if (seg[md] <= g) lo = md + 1; else hi = md; }
        const float cnt = (float)(lo - a);
        out[i] = outagg[i] / fmaxf(cnt, 1.f) + bias[i & 15];
    }
}

extern "C" void kernel_launch(void* const* d_in, const int* in_sizes, int n_in,
                              void* d_out, int out_size, void* d_ws, size_t ws_size,
                              hipStream_t stream) {
    const float* X  = (const float*)d_in[0];
    const float* W  = (const float*)d_in[1];
    const float* bb = (const float*)d_in[2];
    const int* esrc = (const int*)d_in[3];
    const int* edst = (const int*)d_in[4];
    const int* seg  = (const int*)d_in[5];
    const int N = in_sizes[5];                 // 100000
    const int E = in_sizes[3];                 // 3200000
    const int G = out_size / 16;               // 256
    const int NBK = (N + 255) >> 8;            // 391 buckets
    const int NBE = (E + EVB - 1) / EVB;       // 736 scatter blocks
    const int NT = (N + 15) / 16;              // 6250 MFMA row-tiles

    // ws layout (~19 MB; srecs/Hb aliased — srecs dead after k_degnorm)
    unsigned* drecs = (unsigned*)d_ws;                       // NBK*CAP u32 (14.4 MB)
    unsigned* curS  = drecs + (size_t)NBK * CAP;             // NBK  <- memset
    unsigned* curD  = curS + NBK;                            // NBK  <- memset (contig)
    float* nd       = (float*)(curD + NBK);                  // N
    float* ns       = nd + N;                                // N
    float* outagg   = ns + N;                                // G*16 (zeroed by k_scatter)
    unsigned char* srecs = (unsigned char*)(outagg + (size_t)G * 16); // NBK*CAP \ alias
    unsigned short* Hb   = (unsigned short*)srecs;                     // N*16    / region

    hipMemsetAsync(curS, 0, (size_t)2 * NBK * 4, stream);

    k_scatter<<<NBE, CTH, 0, stream>>>(esrc, edst, curS, curD, srecs, drecs,
                                       outagg, E, NBK, G);
    k_degnorm<<<2 * NBK, 256, 0, stream>>>(srecs, drecs, curS, curD, ns, nd, NBK, N);
    k_gemm   <<<1024, 128, 0, stream>>>(X, W, ns, Hb, N, NT);
    k_gaccum <<<NBK * 2, 256, 0, stream>>>(drecs, curD, seg, nd, Hb, outagg, N, G);
    k_final  <<<(G * 16 + 255) / 256, 256, 0, stream>>>(outagg, seg, bb, (float*)d_out, N, G);
}